// Round 1
// baseline (3916.876 us; speedup 1.0000x reference)
//
#include <hip/hip_runtime.h>
#include <math.h>

#define BB 4
#define HH 16
#define SS 1024
#define DD 64

// One block (256 threads = 4 waves) per (b, h, q_row).
// Phase 1: scores for all 1024 k (4 per thread), bias + mask, stable softmax.
// Phase 2: write normalized attn row (coalesced), PV with lane->d mapping.
__global__ __launch_bounds__(256) void attn_fwd_kernel(
    const float* __restrict__ q,
    const float* __restrict__ k,
    const float* __restrict__ v,
    const float* __restrict__ add_attn,
    const int*   __restrict__ mask,
    float* __restrict__ out,       // [B,H,S,D]
    float* __restrict__ attn_out)  // [B,H,S,S]
{
    const int qi  = blockIdx.x;
    const int h   = blockIdx.y;
    const int b   = blockIdx.z;
    const int tid = threadIdx.x;
    const int lane = tid & 63;
    const int wave = tid >> 6;

    __shared__ float q_s[DD];
    __shared__ float p_s[SS];
    __shared__ float red[8];          // [0..3] max per wave, [4..7] sum per wave
    __shared__ float pv_part[4][DD];

    const int bh = b * HH + h;
    const float* qrow  = q + ((size_t)bh * SS + qi) * DD;
    const float* kbase = k + (size_t)bh * SS * DD;
    const float* vbase = v + (size_t)bh * SS * DD;
    const float* bias  = add_attn + ((size_t)b * SS + qi) * SS;
    const int*   mrow  = mask + b * SS;

    if (tid < DD) q_s[tid] = qrow[tid];
    __syncthreads();

    // ---- scores: 4 k-positions per thread ----
    const float scale = 0.125f;  // 1/sqrt(64)
    float sc[4];
#pragma unroll
    for (int j = 0; j < 4; ++j) {
        const int kk = tid + j * 256;
        const float4* kr  = (const float4*)(kbase + (size_t)kk * DD);
        const float4* qs4 = (const float4*)q_s;
        float acc = 0.0f;
#pragma unroll
        for (int dd = 0; dd < DD / 4; ++dd) {
            float4 kv4 = kr[dd];
            float4 qv4 = qs4[dd];
            acc += qv4.x * kv4.x + qv4.y * kv4.y + qv4.z * kv4.z + qv4.w * kv4.w;
        }
        float s = acc * scale + bias[kk];
        if (mrow[kk] == 0) s = -1e9f;
        sc[j] = s;
    }

    // ---- row max (wave shuffle, then cross-wave via LDS) ----
    float m = fmaxf(fmaxf(sc[0], sc[1]), fmaxf(sc[2], sc[3]));
#pragma unroll
    for (int off = 32; off > 0; off >>= 1)
        m = fmaxf(m, __shfl_down(m, off, 64));
    if (lane == 0) red[wave] = m;
    __syncthreads();
    const float rowmax = fmaxf(fmaxf(red[0], red[1]), fmaxf(red[2], red[3]));

    // ---- exp + sum ----
    float lsum = 0.0f;
#pragma unroll
    for (int j = 0; j < 4; ++j) {
        float e = __expf(sc[j] - rowmax);
        p_s[tid + j * 256] = e;
        lsum += e;
    }
#pragma unroll
    for (int off = 32; off > 0; off >>= 1)
        lsum += __shfl_down(lsum, off, 64);
    if (lane == 0) red[4 + wave] = lsum;
    __syncthreads();
    const float inv = 1.0f / (red[4] + red[5] + red[6] + red[7]);

    // ---- normalize + write attn row (coalesced) ----
    float* arow = attn_out + ((size_t)bh * SS + qi) * SS;
#pragma unroll
    for (int j = 0; j < 4; ++j) {
        const int kk = tid + j * 256;
        const float p = p_s[kk] * inv;
        p_s[kk] = p;
        arow[kk] = p;
    }
    __syncthreads();

    // ---- PV: lane -> d (coalesced v reads), 4 k-chunks across waves ----
    const int d     = tid & 63;
    const int chunk = tid >> 6;
    float acc = 0.0f;
    const int k0 = chunk * 256;
    for (int kk = k0; kk < k0 + 256; ++kk)
        acc += p_s[kk] * vbase[(size_t)kk * DD + d];
    pv_part[chunk][d] = acc;
    __syncthreads();
    if (tid < DD) {
        out[((size_t)bh * SS + qi) * DD + tid] =
            pv_part[0][tid] + pv_part[1][tid] + pv_part[2][tid] + pv_part[3][tid];
    }
}

extern "C" void kernel_launch(void* const* d_in, const int* in_sizes, int n_in,
                              void* d_out, int out_size, void* d_ws, size_t ws_size,
                              hipStream_t stream) {
    const float* q        = (const float*)d_in[0];
    const float* k        = (const float*)d_in[1];
    const float* v        = (const float*)d_in[2];
    const float* add_attn = (const float*)d_in[3];
    const int*   mask     = (const int*)d_in[4];

    float* out      = (float*)d_out;                          // B*H*S*D
    float* attn_out = (float*)d_out + (size_t)BB * HH * SS * DD;  // B*H*S*S

    dim3 grid(SS, HH, BB);
    dim3 block(256);
    attn_fwd_kernel<<<grid, block, 0, stream>>>(q, k, v, add_attn, mask, out, attn_out);
}

// Round 2
// 474.569 us; speedup vs baseline: 8.2535x; 8.2535x over previous
//
#include <hip/hip_runtime.h>
#include <math.h>

#define BB 4
#define HH 16
#define SS 1024
#define DD 64
#define QT 16     // q rows per block
#define NKW 4     // waves per block, each owns KPW k-columns
#define KPW 256

typedef __attribute__((ext_vector_type(8))) short bf16x8;
typedef __attribute__((ext_vector_type(4))) float f32x4;

static __device__ inline unsigned short f2bf(float f) {
    unsigned int u = __float_as_uint(f);
    u += 0x7fff + ((u >> 16) & 1);   // RNE
    return (unsigned short)(u >> 16);
}

// ---- pre-pass: fp32 -> bf16 for Q and K (row-major unchanged) ----
__global__ __launch_bounds__(256) void convert_qk(const float* __restrict__ q,
                                                  const float* __restrict__ k,
                                                  unsigned short* __restrict__ qb,
                                                  unsigned short* __restrict__ kb) {
    const int idx = blockIdx.x * 256 + threadIdx.x;     // 1,048,576 float4s
    float4 qv = ((const float4*)q)[idx];
    float4 kv = ((const float4*)k)[idx];
    ushort4 qo = make_ushort4(f2bf(qv.x), f2bf(qv.y), f2bf(qv.z), f2bf(qv.w));
    ushort4 ko = make_ushort4(f2bf(kv.x), f2bf(kv.y), f2bf(kv.z), f2bf(kv.w));
    ((ushort4*)qb)[idx] = qo;
    ((ushort4*)kb)[idx] = ko;
}

// ---- pre-pass: V [bh][k][d] fp32 -> Vt [bh][d][k] bf16 ----
__global__ __launch_bounds__(256) void transpose_v(const float* __restrict__ v,
                                                   unsigned short* __restrict__ vt) {
    const int idx = blockIdx.x * 256 + threadIdx.x;     // over output ushort4s
    const int k  = (idx & 255) * 4;
    const int d  = (idx >> 8) & 63;
    const int bh = idx >> 14;
    const float* vb = v + (size_t)bh * SS * DD;
    ushort4 o = make_ushort4(f2bf(vb[(size_t)(k + 0) * DD + d]),
                             f2bf(vb[(size_t)(k + 1) * DD + d]),
                             f2bf(vb[(size_t)(k + 2) * DD + d]),
                             f2bf(vb[(size_t)(k + 3) * DD + d]));
    ((ushort4*)vt)[idx] = o;
}

// ---- main: per block = (b, h, 16-row q-tile); 4 waves split k ----
__global__ __launch_bounds__(256) void attn_mfma(
    const unsigned short* __restrict__ qb,   // [BH][S][D] bf16
    const unsigned short* __restrict__ kb,   // [BH][S][D] bf16
    const unsigned short* __restrict__ vtb,  // [BH][D][S] bf16
    const float* __restrict__ add_attn,      // [B][S][S]
    const int*   __restrict__ mask,          // [B][S]
    float* __restrict__ out,                 // [BH][S][D]
    float* __restrict__ attn_out)            // [BH][S][S]
{
    const int qt = blockIdx.x, h = blockIdx.y, b = blockIdx.z;
    const int bh = b * HH + h;
    const int tid = threadIdx.x;
    const int wave = tid >> 6;
    const int lane = tid & 63;
    const int col  = lane & 15;      // MFMA C/D col, A-m, B-n
    const int quad = lane >> 4;

    __shared__ unsigned short p_tile[NKW][QT][KPW + 8];
    __shared__ float red_m[NKW][QT];
    __shared__ float red_l[NKW][QT];
    __shared__ float o_part[NKW][QT][DD];

    const int q0  = qt * QT;
    const int wk0 = wave * KPW;

    // A-frags for QK^T: Q[q0+col][quad*8+j (+32)], reused across all k-tiles
    const unsigned short* qrow = qb + ((size_t)bh * SS + q0 + col) * DD + quad * 8;
    const bf16x8 aq0 = *(const bf16x8*)(qrow);
    const bf16x8 aq1 = *(const bf16x8*)(qrow + 32);

    const unsigned short* kbb = kb + (size_t)bh * SS * DD;
    const float* bias = add_attn + ((size_t)b * SS + q0) * SS;
    const int*   mrow = mask + b * SS;

    // ---- QK^T: 16 k-tiles of 16, scores kept in regs (C layout) ----
    float s[16][4];
#pragma unroll
    for (int t = 0; t < 16; ++t) {
        const int k0 = wk0 + t * 16;
        const unsigned short* kr = kbb + (size_t)(k0 + col) * DD + quad * 8;
        bf16x8 bk0 = *(const bf16x8*)(kr);
        bf16x8 bk1 = *(const bf16x8*)(kr + 32);
        f32x4 acc = {0.f, 0.f, 0.f, 0.f};
        acc = __builtin_amdgcn_mfma_f32_16x16x32_bf16(aq0, bk0, acc, 0, 0, 0);
        acc = __builtin_amdgcn_mfma_f32_16x16x32_bf16(aq1, bk1, acc, 0, 0, 0);
        const int kidx = k0 + col;
        const int mv = mrow[kidx];
#pragma unroll
        for (int r = 0; r < 4; ++r) {
            const int qr = quad * 4 + r;
            float sv = acc[r] * 0.125f + bias[(size_t)qr * SS + kidx];
            s[t][r] = (mv == 0) ? -1e9f : sv;
        }
    }

    // ---- row max: per-lane over t, xor-shuffle over the 16-lane col group ----
    float mx[4];
#pragma unroll
    for (int r = 0; r < 4; ++r) {
        float m = s[0][r];
#pragma unroll
        for (int t = 1; t < 16; ++t) m = fmaxf(m, s[t][r]);
        m = fmaxf(m, __shfl_xor(m, 1));
        m = fmaxf(m, __shfl_xor(m, 2));
        m = fmaxf(m, __shfl_xor(m, 4));
        m = fmaxf(m, __shfl_xor(m, 8));
        mx[r] = m;
    }
    if (col == 0) {
#pragma unroll
        for (int r = 0; r < 4; ++r) red_m[wave][quad * 4 + r] = mx[r];
    }
    __syncthreads();
    float mf[4];
#pragma unroll
    for (int r = 0; r < 4; ++r) {
        const int qr = quad * 4 + r;
        mf[r] = fmaxf(fmaxf(red_m[0][qr], red_m[1][qr]),
                      fmaxf(red_m[2][qr], red_m[3][qr]));
    }

    // ---- exp + row sum ----
    float ls[4] = {0.f, 0.f, 0.f, 0.f};
#pragma unroll
    for (int t = 0; t < 16; ++t) {
#pragma unroll
        for (int r = 0; r < 4; ++r) {
            float e = __expf(s[t][r] - mf[r]);
            s[t][r] = e;
            ls[r] += e;
        }
    }
#pragma unroll
    for (int r = 0; r < 4; ++r) {
        float l = ls[r];
        l += __shfl_xor(l, 1);
        l += __shfl_xor(l, 2);
        l += __shfl_xor(l, 4);
        l += __shfl_xor(l, 8);
        ls[r] = l;
    }
    if (col == 0) {
#pragma unroll
        for (int r = 0; r < 4; ++r) red_l[wave][quad * 4 + r] = ls[r];
    }
    __syncthreads();
    float inv[4];
#pragma unroll
    for (int r = 0; r < 4; ++r) {
        const int qr = quad * 4 + r;
        inv[r] = 1.0f / (red_l[0][qr] + red_l[1][qr] + red_l[2][qr] + red_l[3][qr]);
    }

    // ---- normalize, write attn (fp32) + p_tile (bf16, for A-frag re-layout) ----
    float* arow = attn_out + ((size_t)bh * SS + q0) * SS;
#pragma unroll
    for (int t = 0; t < 16; ++t) {
#pragma unroll
        for (int r = 0; r < 4; ++r) {
            const int qr = quad * 4 + r;
            float p = s[t][r] * inv[r];
            arow[(size_t)qr * SS + wk0 + t * 16 + col] = p;
            p_tile[wave][qr][t * 16 + col] = f2bf(p);
        }
    }

    // ---- PV: A = p_tile (wave-local), B = Vt contiguous 16B loads ----
    const unsigned short* vt = vtb + (size_t)bh * DD * SS;
    f32x4 oacc[4];
#pragma unroll
    for (int dc = 0; dc < 4; ++dc) oacc[dc] = (f32x4){0.f, 0.f, 0.f, 0.f};
#pragma unroll
    for (int c = 0; c < 8; ++c) {
        bf16x8 ap = *(const bf16x8*)(&p_tile[wave][col][c * 32 + quad * 8]);
#pragma unroll
        for (int dc = 0; dc < 4; ++dc) {
            const unsigned short* vr =
                vt + (size_t)(dc * 16 + col) * SS + wk0 + c * 32 + quad * 8;
            bf16x8 bv = *(const bf16x8*)(vr);
            oacc[dc] = __builtin_amdgcn_mfma_f32_16x16x32_bf16(ap, bv, oacc[dc], 0, 0, 0);
        }
    }
#pragma unroll
    for (int dc = 0; dc < 4; ++dc)
#pragma unroll
        for (int r = 0; r < 4; ++r)
            o_part[wave][quad * 4 + r][dc * 16 + col] = oacc[dc][r];
    __syncthreads();

    // ---- cross-wave sum + out write ----
    for (int i = tid; i < QT * DD; i += 256) {
        const int qr = i >> 6, d = i & 63;
        out[((size_t)bh * SS + q0 + qr) * DD + d] =
            o_part[0][qr][d] + o_part[1][qr][d] + o_part[2][qr][d] + o_part[3][qr][d];
    }
}

extern "C" void kernel_launch(void* const* d_in, const int* in_sizes, int n_in,
                              void* d_out, int out_size, void* d_ws, size_t ws_size,
                              hipStream_t stream) {
    const float* q        = (const float*)d_in[0];
    const float* k        = (const float*)d_in[1];
    const float* v        = (const float*)d_in[2];
    const float* add_attn = (const float*)d_in[3];
    const int*   mask     = (const int*)d_in[4];

    float* out      = (float*)d_out;
    float* attn_out = (float*)d_out + (size_t)BB * HH * SS * DD;

    const size_t nelem = (size_t)BB * HH * SS * DD;     // 4,194,304
    unsigned short* qb  = (unsigned short*)d_ws;
    unsigned short* kbb = qb + nelem;
    unsigned short* vtb = kbb + nelem;

    convert_qk<<<dim3(nelem / 4 / 256), dim3(256), 0, stream>>>(q, k, qb, kbb);
    transpose_v<<<dim3(nelem / 4 / 256), dim3(256), 0, stream>>>(v, vtb);

    dim3 grid(SS / QT, HH, BB);
    attn_mfma<<<grid, dim3(256), 0, stream>>>(qb, kbb, vtb, add_attn, mask, out, attn_out);
}